// Round 1
// baseline (4952.789 us; speedup 1.0000x reference)
//
#include <hip/hip_runtime.h>
#include <hip/hip_bf16.h>
#include <cmath>

#define NN 25600   // nodes
#define NE 307200  // edges
#define NB 256     // graphs
#define HD 256     // hidden

// ---------- math helpers ----------
__device__ __forceinline__ float ntn_f(float v, float pos, float neg) {
  if (isnan(v)) return 0.f;
  if (isinf(v)) return v > 0.f ? pos : neg;
  return v;
}
__device__ __forceinline__ float ntn_def(float v) {
  if (isnan(v)) return 0.f;
  if (isinf(v)) return v > 0.f ? 3.4028234663852886e38f : -3.4028234663852886e38f;
  return v;
}
__device__ __forceinline__ float sigmoid_f(float x) { return 1.f / (1.f + __expf(-x)); }
__device__ __forceinline__ float silu_f(float x) { return x * sigmoid_f(x); }
__device__ __forceinline__ float softplus_f(float x) {
  return fmaxf(x, 0.f) + log1pf(__expf(-fabsf(x)));
}

template <int NW>
__device__ __forceinline__ float blockSum(float v, float* sred) {
  int lane = threadIdx.x & 63, w = threadIdx.x >> 6;
#pragma unroll
  for (int o = 32; o; o >>= 1) v += __shfl_xor(v, o);
  __syncthreads();  // protect sred reuse
  if (lane == 0) sred[w] = v;
  __syncthreads();
  float r = 0.f;
#pragma unroll
  for (int i = 0; i < NW; ++i) r += sred[i];
  return r;
}

// ---------- CSR build ----------
__global__ void k_hist(const int* __restrict__ dst, int* __restrict__ counts, int E) {
  int e = blockIdx.x * 256 + threadIdx.x;
  if (e < E) atomicAdd(&counts[dst[e]], 1);
}

__global__ __launch_bounds__(1024) void k_scan(const int* __restrict__ counts,
                                               int* __restrict__ offs, int n) {
  __shared__ int sd[1024];
  __shared__ int run;
  int tid = threadIdx.x;
  if (tid == 0) run = 0;
  __syncthreads();
  for (int base = 0; base < n; base += 1024) {
    int i = base + tid;
    int v = (i < n) ? counts[i] : 0;
    sd[tid] = v;
    __syncthreads();
    int acc = v;
    for (int off = 1; off < 1024; off <<= 1) {
      int t = (tid >= off) ? sd[tid - off] : 0;
      __syncthreads();
      acc += t;
      sd[tid] = acc;
      __syncthreads();
    }
    int r = run;
    if (i < n) offs[i] = r + acc - v;  // exclusive
    __syncthreads();
    if (tid == 1023) run = r + sd[1023];
    __syncthreads();
  }
  if (threadIdx.x == 0) offs[n] = run;
}

__global__ void k_scatter(const int* __restrict__ dst, const int* __restrict__ offs,
                          int* __restrict__ cursor, int* __restrict__ eidx, int E) {
  int e = blockIdx.x * 256 + threadIdx.x;
  if (e < E) {
    int d = dst[e];
    int p = offs[d] + atomicAdd(&cursor[d], 1);
    eidx[p] = e;
  }
}

// ---------- GNN input layer ----------
__global__ void k_gin(const float* __restrict__ x, const float* __restrict__ W,
                      const float* __restrict__ bias, float* __restrict__ h) {
  int n = blockIdx.x, j = threadIdx.x;
  float xv[7];
#pragma unroll
  for (int k = 0; k < 7; ++k) xv[k] = ntn_f(x[n * 7 + k], 3.f, -3.f);
  float acc = bias[j];
#pragma unroll
  for (int k = 0; k < 7; ++k) acc += xv[k] * W[k * 256 + j];
  h[(size_t)n * 256 + j] = silu_f(acc);
}

// ---------- per-layer node GEMM: P[N,1024] = h @ {Wf_d, Wf_s, Ws_d, Ws_s} ----------
// grid (M/64, 16), block 256; dst parts get bias baked in.
__global__ __launch_bounds__(256) void k_gemm4(const float* __restrict__ A,
                                               const float* __restrict__ Wf,
                                               const float* __restrict__ Ws,
                                               const float* __restrict__ bf,
                                               const float* __restrict__ bs,
                                               float* __restrict__ P) {
  __shared__ float As[16][68];
  __shared__ float Bs[16][64];
  int tid = threadIdx.x;
  int tx = tid & 15, ty = tid >> 4;
  int mb = blockIdx.x, nb = blockIdx.y;
  int tbl = nb >> 2;
  int jn = (nb & 3) << 6;
  const float* B = (tbl == 0) ? Wf : (tbl == 1) ? (Wf + 65536) : (tbl == 2) ? Ws : (Ws + 65536);
  const float* bias = (tbl == 0) ? bf : (tbl == 2) ? bs : nullptr;
  int m0 = mb << 6;
  float acc[4][4] = {};
  for (int k0 = 0; k0 < 256; k0 += 16) {
    int kk = tid & 15;
    int rr = tid >> 4;
#pragma unroll
    for (int r = 0; r < 4; ++r) {
      int row = rr + r * 16;
      As[kk][row] = A[(size_t)(m0 + row) * 256 + k0 + kk];
    }
    int jj = tid & 63;
    int kr = tid >> 6;
#pragma unroll
    for (int r = 0; r < 4; ++r) {
      int krow = kr + r * 4;
      Bs[krow][jj] = B[(size_t)(k0 + krow) * 256 + jn + jj];
    }
    __syncthreads();
#pragma unroll
    for (int k = 0; k < 16; ++k) {
      float4 a4 = *(const float4*)&As[k][ty * 4];
      float4 b4 = *(const float4*)&Bs[k][tx * 4];
      float av[4] = {a4.x, a4.y, a4.z, a4.w};
      float bv[4] = {b4.x, b4.y, b4.z, b4.w};
#pragma unroll
      for (int i = 0; i < 4; ++i)
#pragma unroll
        for (int j = 0; j < 4; ++j) acc[i][j] += av[i] * bv[j];
    }
    __syncthreads();
  }
#pragma unroll
  for (int i = 0; i < 4; ++i) {
    int row = m0 + ty * 4 + i;
    float4 o;
    float b0 = bias ? bias[jn + tx * 4 + 0] : 0.f;
    float b1 = bias ? bias[jn + tx * 4 + 1] : 0.f;
    float b2 = bias ? bias[jn + tx * 4 + 2] : 0.f;
    float b3 = bias ? bias[jn + tx * 4 + 3] : 0.f;
    o.x = acc[i][0] + b0;
    o.y = acc[i][1] + b1;
    o.z = acc[i][2] + b2;
    o.w = acc[i][3] + b3;
    *(float4*)&P[(size_t)row * 1024 + tbl * 256 + jn + tx * 4] = o;
  }
}

// ---------- fused edge-message + aggregate + residual + LN ----------
// one wave per node (grid-stride). lane l owns dims 4l..4l+3.
__global__ __launch_bounds__(256) void k_edge(
    const float* __restrict__ h, const float* __restrict__ P, const float* __restrict__ ea,
    const int* __restrict__ srcArr, const int* __restrict__ offs, const int* __restrict__ eidx,
    const float* __restrict__ WfE, const float* __restrict__ WsE,
    const float* __restrict__ lng, const float* __restrict__ lnb, float* __restrict__ hout) {
  int lane = threadIdx.x & 63;
  int gw = blockIdx.x * (blockDim.x >> 6) + (threadIdx.x >> 6);
  int nw = gridDim.x * (blockDim.x >> 6);
  float wf[16][4], wsr[16][4];
#pragma unroll
  for (int k = 0; k < 16; ++k) {
    float4 t = *(const float4*)(WfE + k * 256 + lane * 4);
    wf[k][0] = t.x; wf[k][1] = t.y; wf[k][2] = t.z; wf[k][3] = t.w;
    float4 u = *(const float4*)(WsE + k * 256 + lane * 4);
    wsr[k][0] = u.x; wsr[k][1] = u.y; wsr[k][2] = u.z; wsr[k][3] = u.w;
  }
  float4 g4 = *(const float4*)(lng + lane * 4);
  float4 b4 = *(const float4*)(lnb + lane * 4);
  for (int n = gw; n < NN; n += nw) {
    const float* Pn = P + (size_t)n * 1024;
    float4 pfd = *(const float4*)(Pn + lane * 4);        // h[dst]@Wf_d + bf
    float4 psd = *(const float4*)(Pn + 512 + lane * 4);  // h[dst]@Ws_d + bs
    float4 hn4 = *(const float4*)(h + (size_t)n * 256 + lane * 4);
    float acc[4] = {0.f, 0.f, 0.f, 0.f};
    int e1 = offs[n + 1];
    for (int ii = offs[n]; ii < e1; ++ii) {
      int e = eidx[ii];
      int s = srcArr[e];
      const float* Ps = P + (size_t)s * 1024;
      float4 pfs = *(const float4*)(Ps + 256 + lane * 4);
      float4 pss = *(const float4*)(Ps + 768 + lane * 4);
      float eav = (lane < 16) ? ntn_f(ea[(size_t)e * 16 + lane], 1.f, 0.f) : 0.f;
      float af[4] = {pfd.x + pfs.x, pfd.y + pfs.y, pfd.z + pfs.z, pfd.w + pfs.w};
      float as_[4] = {psd.x + pss.x, psd.y + pss.y, psd.z + pss.z, psd.w + pss.w};
#pragma unroll
      for (int k = 0; k < 16; ++k) {
        float c = __shfl(eav, k);
        af[0] += c * wf[k][0]; af[1] += c * wf[k][1];
        af[2] += c * wf[k][2]; af[3] += c * wf[k][3];
        as_[0] += c * wsr[k][0]; as_[1] += c * wsr[k][1];
        as_[2] += c * wsr[k][2]; as_[3] += c * wsr[k][3];
      }
#pragma unroll
      for (int q = 0; q < 4; ++q) acc[q] += sigmoid_f(af[q]) * softplus_f(as_[q]);
    }
    float hv[4] = {hn4.x, hn4.y, hn4.z, hn4.w};
    float t[4], s1 = 0.f, s2 = 0.f;
#pragma unroll
    for (int q = 0; q < 4; ++q) {
      float cv = hv[q] + acc[q];
      t[q] = silu_f(cv) + hv[q];
      s1 += t[q];
      s2 += t[q] * t[q];
    }
#pragma unroll
    for (int o = 32; o; o >>= 1) {
      s1 += __shfl_xor(s1, o);
      s2 += __shfl_xor(s2, o);
    }
    float mean = s1 * (1.f / 256.f);
    float var = s2 * (1.f / 256.f) - mean * mean;
    float inv = rsqrtf(var + 1e-5f);
    float gg[4] = {g4.x, g4.y, g4.z, g4.w};
    float bb[4] = {b4.x, b4.y, b4.z, b4.w};
    float4 o4;
    o4.x = (t[0] - mean) * inv * gg[0] + bb[0];
    o4.y = (t[1] - mean) * inv * gg[1] + bb[1];
    o4.z = (t[2] - mean) * inv * gg[2] + bb[2];
    o4.w = (t[3] - mean) * inv * gg[3] + bb[3];
    *(float4*)(hout + (size_t)n * 256 + lane * 4) = o4;
  }
}

// ---------- pooling ----------
__global__ void k_pool(const float* __restrict__ h, const int* __restrict__ batch,
                       float* __restrict__ pooled, float* __restrict__ cnt) {
  int n = blockIdx.x, j = threadIdx.x;
  int b = batch[n];
  atomicAdd(&pooled[b * 256 + j], h[(size_t)n * 256 + j]);
  if (j == 0) atomicAdd(&cnt[b], 1.f);
}

__global__ void k_zgnn(const float* __restrict__ pooled, const float* __restrict__ cnt,
                       const float* __restrict__ W, const float* __restrict__ bias,
                       float* __restrict__ zf) {
  int b = blockIdx.x, j = threadIdx.x;  // 192 threads
  float rc = 1.f / fmaxf(cnt[b], 1.f);
  float acc = bias[j];
  for (int k = 0; k < 256; ++k) acc += pooled[b * 256 + k] * rc * W[k * 192 + j];
  zf[b * 384 + j] = ntn_def(acc);
}

// ---------- TDA projector (fused, one block per row, 256 thr) ----------
__global__ __launch_bounds__(256) void k_tda(const float* __restrict__ tda,
    const float* __restrict__ W1, const float* __restrict__ b1,
    const float* __restrict__ g1, const float* __restrict__ bb1,
    const float* __restrict__ W2, const float* __restrict__ b2,
    const float* __restrict__ g2, const float* __restrict__ bb2,
    const float* __restrict__ W3, const float* __restrict__ b3, float* __restrict__ zf) {
  __shared__ float sin_[32];
  __shared__ float sa[256];
  __shared__ float sred[4];
  int b = blockIdx.x, tid = threadIdx.x;
  if (tid < 32) sin_[tid] = ntn_f(tda[b * 32 + tid], 3.f, -3.f);
  __syncthreads();
  float v = b1[tid];
#pragma unroll
  for (int k = 0; k < 32; ++k) v += sin_[k] * W1[k * 256 + tid];
  v = silu_f(v);
  float s1 = blockSum<4>(v, sred);
  float s2 = blockSum<4>(v * v, sred);
  float mean = s1 * (1.f / 256.f), var = s2 * (1.f / 256.f) - mean * mean;
  float inv = rsqrtf(var + 1e-5f);
  v = (v - mean) * inv * g1[tid] + bb1[tid];
  sa[tid] = v;
  __syncthreads();
  float v2 = b2[tid];
  for (int k = 0; k < 256; ++k) v2 += sa[k] * W2[k * 256 + tid];
  v2 = silu_f(v2);
  s1 = blockSum<4>(v2, sred);
  s2 = blockSum<4>(v2 * v2, sred);
  mean = s1 * (1.f / 256.f); var = s2 * (1.f / 256.f) - mean * mean;
  inv = rsqrtf(var + 1e-5f);
  v2 = (v2 - mean) * inv * g2[tid] + bb2[tid];
  __syncthreads();
  sa[tid] = v2;
  __syncthreads();
  if (tid < 128) {
    float o = b3[tid];
    for (int k = 0; k < 256; ++k) o += sa[k] * W3[k * 128 + tid];
    zf[b * 384 + 192 + tid] = ntn_def(o);
  }
}

// ---------- MEGNet projector (fused, one block per row, 128 thr) ----------
__global__ __launch_bounds__(128) void k_meg(const float* __restrict__ mg,
    const float* __restrict__ W1, const float* __restrict__ b1,
    const float* __restrict__ g1, const float* __restrict__ bb1,
    const float* __restrict__ W2, const float* __restrict__ b2,
    const float* __restrict__ g2, const float* __restrict__ bb2,
    const float* __restrict__ W3, const float* __restrict__ b3, float* __restrict__ zf) {
  __shared__ float sin_[16];
  __shared__ float sa[128];
  __shared__ float sred[2];
  int b = blockIdx.x, tid = threadIdx.x;
  if (tid < 16) sin_[tid] = ntn_f(mg[b * 16 + tid], 3.f, -3.f);
  __syncthreads();
  float v = b1[tid];
#pragma unroll
  for (int k = 0; k < 16; ++k) v += sin_[k] * W1[k * 128 + tid];
  v = silu_f(v);
  float s1 = blockSum<2>(v, sred);
  float s2 = blockSum<2>(v * v, sred);
  float mean = s1 * (1.f / 128.f), var = s2 * (1.f / 128.f) - mean * mean;
  float inv = rsqrtf(var + 1e-5f);
  v = (v - mean) * inv * g1[tid] + bb1[tid];
  sa[tid] = v;
  __syncthreads();
  float v2 = b2[tid];
  for (int k = 0; k < 128; ++k) v2 += sa[k] * W2[k * 128 + tid];
  v2 = silu_f(v2);
  s1 = blockSum<2>(v2, sred);
  s2 = blockSum<2>(v2 * v2, sred);
  mean = s1 * (1.f / 128.f); var = s2 * (1.f / 128.f) - mean * mean;
  inv = rsqrtf(var + 1e-5f);
  v2 = (v2 - mean) * inv * g2[tid] + bb2[tid];
  __syncthreads();
  sa[tid] = v2;
  __syncthreads();
  if (tid < 64) {
    float o = b3[tid];
    for (int k = 0; k < 128; ++k) o += sa[k] * W3[k * 64 + tid];
    zf[b * 384 + 320 + tid] = ntn_def(o);
  }
}

// ---------- fusion LN → d_out z ----------
__global__ __launch_bounds__(384) void k_fln(const float* __restrict__ zf,
                                             const float* __restrict__ g,
                                             const float* __restrict__ bb,
                                             float* __restrict__ zout) {
  __shared__ float sred[6];
  int b = blockIdx.x, tid = threadIdx.x;
  float v = zf[b * 384 + tid];
  float s1 = blockSum<6>(v, sred);
  float s2 = blockSum<6>(v * v, sred);
  float mean = s1 * (1.f / 384.f), var = s2 * (1.f / 384.f) - mean * mean;
  float inv = rsqrtf(var + 1e-5f);
  zout[(size_t)b * 384 + tid] = (v - mean) * inv * g[tid] + bb[tid];
}

// ---------- CPPN head ----------
__global__ __launch_bounds__(384) void k_cppn(const float* __restrict__ zall,
    const float* __restrict__ g1W, const float* __restrict__ g1b,
    const float* __restrict__ hg, const float* __restrict__ hb,
    const float* __restrict__ g2W, const float* __restrict__ g2b,
    const float* __restrict__ g3W, const float* __restrict__ g3b,
    const float* __restrict__ plW, const float* __restrict__ plb,
    const float* __restrict__ pq1W, const float* __restrict__ pq1b,
    const float* __restrict__ pq2W, const float* __restrict__ pq2b,
    const float* __restrict__ pc1W, const float* __restrict__ pc1b,
    const float* __restrict__ pc2W, const float* __restrict__ pc2b,
    float* __restrict__ y) {
  __shared__ float sz[384];
  __shared__ float sred[6];
  __shared__ float sg[48];
  __shared__ float s24[24];
  __shared__ float gates[6];
  __shared__ float lin[6];
  __shared__ float qv[6], cvv[6];
  __shared__ float mn, iv;
  int b = blockIdx.x, tid = threadIdx.x;
  sz[tid] = zall[(size_t)b * 384 + tid];
  __syncthreads();
  // gate MLP
  if (tid < 48) {
    float a = g1b[tid];
    for (int k = 0; k < 384; ++k) a += sz[k] * g1W[k * 48 + tid];
    sg[tid] = silu_f(a);
  }
  __syncthreads();
  if (tid == 0) {
    float s = 0.f, s2 = 0.f;
    for (int i = 0; i < 48; ++i) { s += sg[i]; s2 += sg[i] * sg[i]; }
    mn = s * (1.f / 48.f);
    float var = s2 * (1.f / 48.f) - mn * mn;
    iv = rsqrtf(var + 1e-5f);
  }
  __syncthreads();
  if (tid < 48) sg[tid] = (sg[tid] - mn) * iv * hg[tid] + hb[tid];
  __syncthreads();
  if (tid < 24) {
    float a = g2b[tid];
    for (int k = 0; k < 48; ++k) a += sg[k] * g2W[k * 24 + tid];
    s24[tid] = silu_f(a);
  }
  __syncthreads();
  if (tid < 6) {
    float a = g3b[tid];
    for (int k = 0; k < 24; ++k) a += s24[k] * g3W[k * 6 + tid];
    gates[tid] = a;
  }
  __syncthreads();
  if (tid == 0) {
    float mx = gates[0];
    for (int i = 1; i < 6; ++i) mx = fmaxf(mx, gates[i]);
    float s = 0.f;
    for (int i = 0; i < 6; ++i) { gates[i] = __expf(gates[i] - mx); s += gates[i]; }
    float rs = 1.f / s;
    for (int i = 0; i < 6; ++i) gates[i] *= rs;
  }
  // lin: wave w owns branch k=w
  {
    int w = tid >> 6, lane = tid & 63;
    float p = 0.f;
    for (int d = lane; d < 384; d += 64) p += sz[d] * plW[w * 384 + d];
#pragma unroll
    for (int o = 32; o; o >>= 1) p += __shfl_xor(p, o);
    if (lane == 0) lin[w] = p + plb[w];
  }
  // quadratic and cubic branches
  for (int k = 0; k < 6; ++k) {
    float hq = 0.f;
    if (tid < 192) {
      float a = pq1b[k * 192 + tid];
      for (int d = 0; d < 384; ++d) a += sz[d] * pq1W[((size_t)k * 384 + d) * 192 + tid];
      hq = silu_f(a) * pq2W[k * 192 + tid];
    }
    float qs = blockSum<6>(hq, sred);
    if (tid == 0) qv[k] = qs + pq2b[k];
    float hc = 0.f;
    if (tid < 96) {
      float a = pc1b[k * 96 + tid];
      for (int d = 0; d < 384; ++d) a += sz[d] * pc1W[((size_t)k * 384 + d) * 96 + tid];
      float sl = silu_f(a);
      hc = sl * sl * pc2W[k * 96 + tid];
    }
    float cs = blockSum<6>(hc, sred);
    if (tid == 0) cvv[k] = cs + pc2b[k];
  }
  __syncthreads();
  if (tid == 0) {
    float yy = 0.f;
    for (int k = 0; k < 6; ++k) yy += gates[k] * (lin[k] + qv[k] + cvv[k]);
    y[b] = yy;
  }
}

extern "C" void kernel_launch(void* const* d_in, const int* in_sizes, int n_in,
                              void* d_out, int out_size, void* d_ws, size_t ws_size,
                              hipStream_t stream) {
  const float* x         = (const float*)d_in[0];
  const float* edge_attr = (const float*)d_in[1];
  const float* tda       = (const float*)d_in[2];
  const float* megnet    = (const float*)d_in[3];
  const int*   edge_index= (const int*)d_in[4];
  const int*   batch     = (const int*)d_in[5];
  const float* gin_W = (const float*)d_in[6];
  const float* gin_b = (const float*)d_in[7];
  const float* conv_Wf = (const float*)d_in[8];
  const float* conv_bf = (const float*)d_in[9];
  const float* conv_Ws = (const float*)d_in[10];
  const float* conv_bs = (const float*)d_in[11];
  const float* gln_g = (const float*)d_in[12];
  const float* gln_b = (const float*)d_in[13];
  const float* gout_W = (const float*)d_in[14];
  const float* gout_b = (const float*)d_in[15];
  const float* t1_W = (const float*)d_in[16];
  const float* t1_b = (const float*)d_in[17];
  const float* tln1_g = (const float*)d_in[18];
  const float* tln1_b = (const float*)d_in[19];
  const float* t2_W = (const float*)d_in[20];
  const float* t2_b = (const float*)d_in[21];
  const float* tln2_g = (const float*)d_in[22];
  const float* tln2_b = (const float*)d_in[23];
  const float* t3_W = (const float*)d_in[24];
  const float* t3_b = (const float*)d_in[25];
  const float* m1_W = (const float*)d_in[26];
  const float* m1_b = (const float*)d_in[27];
  const float* mln1_g = (const float*)d_in[28];
  const float* mln1_b = (const float*)d_in[29];
  const float* m2_W = (const float*)d_in[30];
  const float* m2_b = (const float*)d_in[31];
  const float* mln2_g = (const float*)d_in[32];
  const float* mln2_b = (const float*)d_in[33];
  const float* m3_W = (const float*)d_in[34];
  const float* m3_b = (const float*)d_in[35];
  const float* fln_g = (const float*)d_in[36];
  const float* fln_b = (const float*)d_in[37];
  const float* g1_W = (const float*)d_in[38];
  const float* g1_b = (const float*)d_in[39];
  const float* hln_g = (const float*)d_in[40];
  const float* hln_b = (const float*)d_in[41];
  const float* g2_W = (const float*)d_in[42];
  const float* g2_b = (const float*)d_in[43];
  const float* g3_W = (const float*)d_in[44];
  const float* g3_b = (const float*)d_in[45];
  const float* plin_W = (const float*)d_in[46];
  const float* plin_b = (const float*)d_in[47];
  const float* pq1_W = (const float*)d_in[48];
  const float* pq1_b = (const float*)d_in[49];
  const float* pq2_W = (const float*)d_in[50];
  const float* pq2_b = (const float*)d_in[51];
  const float* pc1_W = (const float*)d_in[52];
  const float* pc1_b = (const float*)d_in[53];
  const float* pc2_W = (const float*)d_in[54];
  const float* pc2_b = (const float*)d_in[55];

  // workspace layout (floats then ints); total ≈ 160 MB
  float* ws = (float*)d_ws;
  float* hA = ws;
  float* hB = hA + (size_t)NN * 256;
  float* P  = hB + (size_t)NN * 256;       // [NN, 1024]
  float* pooled = P + (size_t)NN * 1024;   // [NB, 256]
  float* cnt = pooled + (size_t)NB * 256;  // [NB]
  float* zf  = cnt + NB;                   // [NB, 384]
  int* counts = (int*)(zf + (size_t)NB * 384);  // [NN]
  int* cursor = counts + NN;                    // [NN]
  int* offs   = cursor + NN;                    // [NN+1]
  int* eidx   = offs + NN + 1;                  // [NE]

  const int* srcArr = edge_index;       // row 0 = src
  const int* dstArr = edge_index + NE;  // row 1 = dst

  hipMemsetAsync(counts, 0, (size_t)2 * NN * sizeof(int), stream);  // counts+cursor
  hipMemsetAsync(pooled, 0, ((size_t)NB * 256 + NB) * sizeof(float), stream);

  k_hist<<<(NE + 255) / 256, 256, 0, stream>>>(dstArr, counts, NE);
  k_scan<<<1, 1024, 0, stream>>>(counts, offs, NN);
  k_scatter<<<(NE + 255) / 256, 256, 0, stream>>>(dstArr, offs, cursor, eidx, NE);

  k_gin<<<NN, 256, 0, stream>>>(x, gin_W, gin_b, hA);

  float* hcur = hA;
  float* hnext = hB;
  for (int i = 0; i < 6; ++i) {
    const float* Wf = conv_Wf + (size_t)i * 528 * 256;
    const float* Ws = conv_Ws + (size_t)i * 528 * 256;
    const float* bf = conv_bf + i * 256;
    const float* bs = conv_bs + i * 256;
    k_gemm4<<<dim3(NN / 64, 16), 256, 0, stream>>>(hcur, Wf, Ws, bf, bs, P);
    k_edge<<<800, 256, 0, stream>>>(hcur, P, edge_attr, srcArr, offs, eidx,
                                    Wf + 512 * 256, Ws + 512 * 256,
                                    gln_g + i * 256, gln_b + i * 256, hnext);
    float* tmp = hcur; hcur = hnext; hnext = tmp;
  }

  k_pool<<<NN, 256, 0, stream>>>(hcur, batch, pooled, cnt);
  k_zgnn<<<NB, 192, 0, stream>>>(pooled, cnt, gout_W, gout_b, zf);
  k_tda<<<NB, 256, 0, stream>>>(tda, t1_W, t1_b, tln1_g, tln1_b, t2_W, t2_b, tln2_g, tln2_b,
                                t3_W, t3_b, zf);
  k_meg<<<NB, 128, 0, stream>>>(megnet, m1_W, m1_b, mln1_g, mln1_b, m2_W, m2_b, mln2_g, mln2_b,
                                m3_W, m3_b, zf);

  float* yout = (float*)d_out;
  float* zout = yout + NB;  // z output [NB,384] right after y [NB]
  k_fln<<<NB, 384, 0, stream>>>(zf, fln_g, fln_b, zout);
  k_cppn<<<NB, 384, 0, stream>>>(zout, g1_W, g1_b, hln_g, hln_b, g2_W, g2_b, g3_W, g3_b,
                                 plin_W, plin_b, pq1_W, pq1_b, pq2_W, pq2_b,
                                 pc1_W, pc1_b, pc2_W, pc2_b, yout);
}